// Round 11
// baseline (394.125 us; speedup 1.0000x reference)
//
#include <hip/hip_runtime.h>
#include <stdint.h>

// Problem constants
#define BT_N  32      // B*T
#define SEQL  512     // S
#define DM    768     // D_MODEL
#define NHEAD 12
#define HDIM  64
#define MTOT  (BT_N * SEQL)   // 16384 rows

typedef __bf16 bf16x8 __attribute__((ext_vector_type(8)));
typedef float  f32x4  __attribute__((ext_vector_type(4)));

__device__ __forceinline__ float b2f(uint16_t u)  { return __uint_as_float(((uint32_t)u) << 16); }
__device__ __forceinline__ uint16_t f2b(float f) {
    uint32_t u = __float_as_uint(f);
    return (uint16_t)((u + 0x7fffu + ((u >> 16) & 1u)) >> 16);  // RNE
}
__device__ __forceinline__ void split_bf16(float x, uint16_t& hi, uint16_t& lo) {
    hi = f2b(x);
    lo = f2b(x - b2f(hi));
}

// global -> LDS DMA, 16 B per lane. LDS dest must be wave-uniform base (+lane*16 implicit).
__device__ __forceinline__ void gload16(const void* g, void* l) {
    __builtin_amdgcn_global_load_lds(
        (const __attribute__((address_space(1))) void*)g,
        (__attribute__((address_space(3))) void*)l,
        16, 0, 0);
}

// ---------------------------------------------------------------------------
// Fused prepass: blocks [0,12288) = X fp32 -> Xh/Xl split;
// [12288,14592) = weight transpose (+split for Wq,Wk).
// ---------------------------------------------------------------------------
__global__ __launch_bounds__(256) void prep_kernel(
    const float* __restrict__ X, uint16_t* __restrict__ Xh, uint16_t* __restrict__ Xl,
    const float* __restrict__ Wq, const float* __restrict__ Wk,
    const float* __restrict__ Wv, const float* __restrict__ Wo,
    uint16_t* __restrict__ WqTh, uint16_t* __restrict__ WqTl,
    uint16_t* __restrict__ WkTh, uint16_t* __restrict__ WkTl,
    uint16_t* __restrict__ WvT,  uint16_t* __restrict__ WoT)
{
    __shared__ float tile[32][33];
    const int bid = blockIdx.x;
    const int tid = threadIdx.x;

    if (bid < 12288) {                       // ---- split_x ----
        size_t i = ((size_t)bid * 256 + tid) * 4;
        float4 v = *(const float4*)(X + i);
        float xx[4] = {v.x, v.y, v.z, v.w};
        ushort4 h, l;
        uint16_t hh, ll;
        split_bf16(xx[0], hh, ll); h.x = hh; l.x = ll;
        split_bf16(xx[1], hh, ll); h.y = hh; l.y = ll;
        split_bf16(xx[2], hh, ll); h.z = hh; l.z = ll;
        split_bf16(xx[3], hh, ll); h.w = hh; l.w = ll;
        *(ushort4*)(Xh + i) = h;
        *(ushort4*)(Xl + i) = l;
        return;
    }

    // ---- wprep ----
    const int wid = bid - 12288;             // 0..2303
    const int z   = wid / 576;
    const int rem = wid % 576;
    const int k0 = (rem % 24) * 32, n0 = (rem / 24) * 32;

    const float* W; uint16_t* Th; uint16_t* Tl;
    if (z == 0)      { W = Wq; Th = WqTh; Tl = WqTl; }
    else if (z == 1) { W = Wk; Th = WkTh; Tl = WkTl; }
    else if (z == 2) { W = Wv; Th = WvT;  Tl = nullptr; }
    else             { W = Wo; Th = WoT;  Tl = nullptr; }

    {
        int r = tid >> 3, c = (tid & 7) * 4;
        *(float4*)&tile[r][c] = *(const float4*)(W + (size_t)(k0 + r) * DM + n0 + c);
    }
    __syncthreads();
    {
        int nl = tid >> 3, kk = (tid & 7) * 4;
        ushort4 h, l;
        uint16_t hh, ll;
        float v0 = tile[kk + 0][nl], v1 = tile[kk + 1][nl];
        float v2 = tile[kk + 2][nl], v3 = tile[kk + 3][nl];
        split_bf16(v0, hh, ll); h.x = hh; l.x = ll;
        split_bf16(v1, hh, ll); h.y = hh; l.y = ll;
        split_bf16(v2, hh, ll); h.z = hh; l.z = ll;
        split_bf16(v3, hh, ll); h.w = hh; l.w = ll;
        size_t o = (size_t)(n0 + nl) * DM + k0 + kk;
        *(ushort4*)(Th + o) = h;
        if (Tl) *(ushort4*)(Tl + o) = l;
    }
}

// ---------------------------------------------------------------------------
// Fused QKV GEMM v8 = v7 (concatenated qk|V) + counted-vmcnt dual-barrier
// k-loop: stage(next) -> vmcnt(8) -> s_barrier -> compute(cur) ->
// lgkmcnt(0)+sched_barrier -> s_barrier. Next tile's 8 loads stay in flight
// ACROSS the barrier (never drain to 0 in the main loop). Math byte-identical
// to v7; only waits/barriers changed.
// ---------------------------------------------------------------------------
__global__ __launch_bounds__(256, 2) void qkv_gemm_v8(
    const uint16_t* __restrict__ Xh, const uint16_t* __restrict__ Xl,
    const uint16_t* __restrict__ WqTh, const uint16_t* __restrict__ WqTl,
    const uint16_t* __restrict__ WkTh, const uint16_t* __restrict__ WkTl,
    const uint16_t* __restrict__ WvT,
    const float* __restrict__ bq, const float* __restrict__ bk,
    const float* __restrict__ bv,
    uint16_t* __restrict__ Qh, uint16_t* __restrict__ Ql,
    uint16_t* __restrict__ Kh, uint16_t* __restrict__ Kl,
    uint16_t* __restrict__ Vt)
{
    __shared__ uint16_t lds[2][16384];   // 2 x 32 KB

    const int bid  = blockIdx.x;
    const int tid  = threadIdx.x;
    const int lane = tid & 63, wave = tid >> 6;
    const int quad = lane >> 4, l16 = lane & 15;
    const int wm = (wave >> 1) * 64, wn = (wave & 1) * 64;

    if (bid < 1536) {
        // ================= QK path (split-bf16), x-fastest order =================
        const int m0 = (bid & 127) * 128;
        const int n0 = ((bid >> 7) % 6) * 128;
        const int z  = bid / 768;

        const uint16_t* Bh_g = z ? WkTh : WqTh;
        const uint16_t* Bl_g = z ? WkTl : WqTl;
        const float* bias    = z ? bk : bq;
        uint16_t* OutH       = z ? Kh : Qh;
        uint16_t* OutL       = z ? Kl : Ql;
        const float scale    = z ? 1.0f : 0.125f;

        const uint16_t* src[8];
        #pragma unroll
        for (int i = 0; i < 8; i++) {
            int d    = (i * 256 + tid) * 16;
            int row  = (d >> 7) & 127;
            int colb = d & 127;
            int scol = colb ^ ((row & 7) << 4);      // involution
            int kofs = (scol & 63) >> 1;             // 0..31 elems within k-window
            const uint16_t* g;
            if (d < 16384) g = (scol < 64 ? Xh : Xl)     + (size_t)(m0 + row) * DM + kofs;
            else           g = (scol < 64 ? Bh_g : Bl_g) + (size_t)(n0 + row) * DM + kofs;
            src[i] = g;
        }

        int offA[4], offB[4];
        #pragma unroll
        for (int i = 0; i < 4; i++) {
            int r  = wm + i * 16 + l16;
            offA[i] = r * 64 + (((quad * 16) ^ ((r & 7) << 4)) >> 1);
            int rb = wn + i * 16 + l16;
            offB[i] = 8192 + rb * 64 + (((quad * 16) ^ ((rb & 7) << 4)) >> 1);
        }

        f32x4 acc[4][4];
        #pragma unroll
        for (int i = 0; i < 4; i++)
            #pragma unroll
            for (int j = 0; j < 4; j++) acc[i][j] = (f32x4){0.f,0.f,0.f,0.f};

        auto stage = [&](int buf) {
            #pragma unroll
            for (int i = 0; i < 8; i++) {
                gload16(src[i], &lds[buf][(i * 256 + wave * 64) * 8]);
                src[i] += 32;                        // advance one BK=32 window
            }
        };
        auto computeTile = [&](int buf) {
            const uint16_t* base = &lds[buf][0];
            bf16x8 ah[4], al[4], bh[4], bl[4];
            #pragma unroll
            for (int i = 0; i < 4; i++) {
                ah[i] = *(const bf16x8*)(base + offA[i]);
                al[i] = *(const bf16x8*)(base + (offA[i] ^ 32));
                bh[i] = *(const bf16x8*)(base + offB[i]);
                bl[i] = *(const bf16x8*)(base + (offB[i] ^ 32));
            }
            #pragma unroll
            for (int mi = 0; mi < 4; mi++)
                #pragma unroll
                for (int ni = 0; ni < 4; ni++) {
                    acc[mi][ni] = __builtin_amdgcn_mfma_f32_16x16x32_bf16(al[mi], bh[ni], acc[mi][ni], 0, 0, 0);
                    acc[mi][ni] = __builtin_amdgcn_mfma_f32_16x16x32_bf16(ah[mi], bl[ni], acc[mi][ni], 0, 0, 0);
                    acc[mi][ni] = __builtin_amdgcn_mfma_f32_16x16x32_bf16(ah[mi], bh[ni], acc[mi][ni], 0, 0, 0);
                }
        };

        stage(0);
        int cur = 0;
        #pragma unroll 1
        for (int t = 0; t < 23; t++) {               // compute tiles 0..22
            stage(cur ^ 1);                          // issue tile t+1 (stays in flight)
            asm volatile("s_waitcnt vmcnt(8)" ::: "memory");  // tile t's loads done
            __builtin_amdgcn_s_barrier();            // all waves: tile t visible
            computeTile(cur);
            asm volatile("s_waitcnt lgkmcnt(0)" ::: "memory"); // my ds_reads retired
            __builtin_amdgcn_sched_barrier(0);
            __builtin_amdgcn_s_barrier();            // release buf cur for overwrite
            cur ^= 1;
        }
        asm volatile("s_waitcnt vmcnt(0)" ::: "memory");       // tile 23 loads done
        __builtin_amdgcn_s_barrier();
        computeTile(cur);

        // epilogue: split-bf16 store to (bt,h,s,d)
        #pragma unroll
        for (int i = 0; i < 4; i++) {
            #pragma unroll
            for (int j = 0; j < 4; j++) {
                int n = n0 + wn + j * 16 + l16;
                float bsv = bias[n];
                int hh = n >> 6, dd = n & 63;
                int mb = m0 + wm + i * 16 + quad * 4;
                #pragma unroll
                for (int r = 0; r < 4; r++) {
                    int m = mb + r;
                    float val = (acc[i][j][r] + bsv) * scale;
                    uint16_t vh, vl; split_bf16(val, vh, vl);
                    int bt = m >> 9, s = m & 511;
                    size_t idx = (((size_t)bt * NHEAD + hh) * SEQL + s) * HDIM + dd;
                    OutH[idx] = vh; OutL[idx] = vl;
                }
            }
        }
    } else {
        // ================= V path (plain bf16), XCD swizzle =================
        const int v_id = bid - 1536;                 // 0..767
        const int wg  = (v_id & 7) * 96 + (v_id >> 3);
        const int m0  = (wg / 6) * 128;
        const int n0  = (wg % 6) * 128;

        const uint16_t* src[8];
        #pragma unroll
        for (int i = 0; i < 8; i++) {
            int d    = (i * 256 + tid) * 16;
            int row  = (d >> 7) & 127;
            int colb = d & 127;
            int scol = colb ^ ((row & 7) << 4);
            int kofs = scol >> 1;                    // 0..63
            src[i] = (d < 16384 ? Xh + (size_t)(m0 + row) * DM
                                : WvT + (size_t)(n0 + row) * DM) + kofs;
        }

        int offA[4], offB[4];
        #pragma unroll
        for (int i = 0; i < 4; i++) {
            int r  = wm + i * 16 + l16;
            offA[i] = r * 64 + (((quad * 16) ^ ((r & 7) << 4)) >> 1);
            int rb = wn + i * 16 + l16;
            offB[i] = 8192 + rb * 64 + (((quad * 16) ^ ((rb & 7) << 4)) >> 1);
        }

        f32x4 acc[4][4];
        #pragma unroll
        for (int i = 0; i < 4; i++)
            #pragma unroll
            for (int j = 0; j < 4; j++) acc[i][j] = (f32x4){0.f,0.f,0.f,0.f};

        auto stage = [&](int buf) {
            #pragma unroll
            for (int i = 0; i < 8; i++) {
                gload16(src[i], &lds[buf][(i * 256 + wave * 64) * 8]);
                src[i] += 64;
            }
        };
        auto computeTile = [&](int buf) {
            const uint16_t* base = &lds[buf][0];
            bf16x8 a0[4], a1[4], b0[4], b1[4];
            #pragma unroll
            for (int i = 0; i < 4; i++) {
                a0[i] = *(const bf16x8*)(base + offA[i]);
                a1[i] = *(const bf16x8*)(base + (offA[i] ^ 32));
                b0[i] = *(const bf16x8*)(base + offB[i]);
                b1[i] = *(const bf16x8*)(base + (offB[i] ^ 32));
            }
            #pragma unroll
            for (int mi = 0; mi < 4; mi++)
                #pragma unroll
                for (int ni = 0; ni < 4; ni++)
                    acc[mi][ni] = __builtin_amdgcn_mfma_f32_16x16x32_bf16(a0[mi], b0[ni], acc[mi][ni], 0, 0, 0);
            #pragma unroll
            for (int mi = 0; mi < 4; mi++)
                #pragma unroll
                for (int ni = 0; ni < 4; ni++)
                    acc[mi][ni] = __builtin_amdgcn_mfma_f32_16x16x32_bf16(a1[mi], b1[ni], acc[mi][ni], 0, 0, 0);
        };

        stage(0);
        int cur = 0;
        #pragma unroll 1
        for (int t = 0; t < 11; t++) {               // compute tiles 0..10
            stage(cur ^ 1);
            asm volatile("s_waitcnt vmcnt(8)" ::: "memory");
            __builtin_amdgcn_s_barrier();
            computeTile(cur);
            asm volatile("s_waitcnt lgkmcnt(0)" ::: "memory");
            __builtin_amdgcn_sched_barrier(0);
            __builtin_amdgcn_s_barrier();
            cur ^= 1;
        }
        asm volatile("s_waitcnt vmcnt(0)" ::: "memory");
        __builtin_amdgcn_s_barrier();
        computeTile(cur);

        #pragma unroll
        for (int i = 0; i < 4; i++) {
            #pragma unroll
            for (int j = 0; j < 4; j++) {
                int n = n0 + wn + j * 16 + l16;
                float bsv = bv[n];
                int hh = n >> 6, dd = n & 63;
                int mb = m0 + wm + i * 16 + quad * 4;
                int bt = mb >> 9, sb = mb & 511;
                ushort4 pk;
                pk.x = f2b(acc[i][j][0] + bsv);
                pk.y = f2b(acc[i][j][1] + bsv);
                pk.z = f2b(acc[i][j][2] + bsv);
                pk.w = f2b(acc[i][j][3] + bsv);
                *(ushort4*)&Vt[(((size_t)bt * NHEAD + hh) * HDIM + dd) * SEQL + sb] = pk;
            }
        }
    }
}

// ---------------------------------------------------------------------------
// Output projection v4: 2-buffer + counted-vmcnt dual-barrier (same schedule
// change as qkv v8). XCD swizzle (grid 768 1D). Math identical to v3.
// ---------------------------------------------------------------------------
__global__ __launch_bounds__(256, 2) void out_proj_v4(
    const uint16_t* __restrict__ A, const uint16_t* __restrict__ WoT,
    const float* __restrict__ bias, float* __restrict__ Y)
{
    __shared__ uint16_t lds[2][16384];

    const int bid = blockIdx.x;
    const int wg  = (bid & 7) * 96 + (bid >> 3);
    const int m0  = (wg / 6) * 128;
    const int n0  = (wg % 6) * 128;

    const int tid  = threadIdx.x;
    const int lane = tid & 63, wave = tid >> 6;
    const int quad = lane >> 4, l16 = lane & 15;
    const int wm = (wave >> 1) * 64, wn = (wave & 1) * 64;

    const uint16_t* src[8];
    #pragma unroll
    for (int i = 0; i < 8; i++) {
        int d    = (i * 256 + tid) * 16;
        int row  = (d >> 7) & 127;
        int colb = d & 127;
        int scol = colb ^ ((row & 7) << 4);
        int kofs = scol >> 1;
        src[i] = (d < 16384 ? A + (size_t)(m0 + row) * DM
                            : WoT + (size_t)(n0 + row) * DM) + kofs;
    }

    int offA[4], offB[4];
    #pragma unroll
    for (int i = 0; i < 4; i++) {
        int r  = wm + i * 16 + l16;
        offA[i] = r * 64 + (((quad * 16) ^ ((r & 7) << 4)) >> 1);
        int rb = wn + i * 16 + l16;
        offB[i] = 8192 + rb * 64 + (((quad * 16) ^ ((rb & 7) << 4)) >> 1);
    }

    f32x4 acc[4][4];
    #pragma unroll
    for (int i = 0; i < 4; i++)
        #pragma unroll
        for (int j = 0; j < 4; j++) acc[i][j] = (f32x4){0.f,0.f,0.f,0.f};

    auto stage = [&](int buf) {
        #pragma unroll
        for (int i = 0; i < 8; i++) {
            gload16(src[i], &lds[buf][(i * 256 + wave * 64) * 8]);
            src[i] += 64;
        }
    };
    auto computeTile = [&](int buf) {
        const uint16_t* base = &lds[buf][0];
        bf16x8 a0[4], a1[4], b0[4], b1[4];
        #pragma unroll
        for (int i = 0; i < 4; i++) {
            a0[i] = *(const bf16x8*)(base + offA[i]);
            a1[i] = *(const bf16x8*)(base + (offA[i] ^ 32));
            b0[i] = *(const bf16x8*)(base + offB[i]);
            b1[i] = *(const bf16x8*)(base + (offB[i] ^ 32));
        }
        #pragma unroll
        for (int mi = 0; mi < 4; mi++)
            #pragma unroll
            for (int ni = 0; ni < 4; ni++)
                acc[mi][ni] = __builtin_amdgcn_mfma_f32_16x16x32_bf16(a0[mi], b0[ni], acc[mi][ni], 0, 0, 0);
        #pragma unroll
        for (int mi = 0; mi < 4; mi++)
            #pragma unroll
            for (int ni = 0; ni < 4; ni++)
                acc[mi][ni] = __builtin_amdgcn_mfma_f32_16x16x32_bf16(a1[mi], b1[ni], acc[mi][ni], 0, 0, 0);
    };

    stage(0);
    int cur = 0;
    #pragma unroll 1
    for (int t = 0; t < 11; t++) {
        stage(cur ^ 1);
        asm volatile("s_waitcnt vmcnt(8)" ::: "memory");
        __builtin_amdgcn_s_barrier();
        computeTile(cur);
        asm volatile("s_waitcnt lgkmcnt(0)" ::: "memory");
        __builtin_amdgcn_sched_barrier(0);
        __builtin_amdgcn_s_barrier();
        cur ^= 1;
    }
    asm volatile("s_waitcnt vmcnt(0)" ::: "memory");
    __builtin_amdgcn_s_barrier();
    computeTile(cur);

    #pragma unroll
    for (int i = 0; i < 4; i++) {
        #pragma unroll
        for (int j = 0; j < 4; j++) {
            int n = n0 + wn + j * 16 + l16;
            float bsv = bias[n];
            int mb = m0 + wm + i * 16 + quad * 4;
            #pragma unroll
            for (int r = 0; r < 4; r++)
                Y[(size_t)(mb + r) * DM + n] = acc[i][j][r] + bsv;
        }
    }
}

// ---------------------------------------------------------------------------
// MFMA flash attention v4 (unchanged): LDS staging + T14 async-STAGE split,
// tile skip, defer-max, XCD swizzle.
// ---------------------------------------------------------------------------
#define QTILE 64

__global__ __launch_bounds__(256) void attn_mfma_v4(
    const uint16_t* __restrict__ Qhg, const uint16_t* __restrict__ Qlg,
    const uint16_t* __restrict__ Khg, const uint16_t* __restrict__ Klg,
    const uint16_t* __restrict__ Vtg, const int* __restrict__ modality,
    const int* __restrict__ nlat_p, uint16_t* __restrict__ ctx)
{
    __shared__ uint16_t KhS[64][72];   // K chunk hi [key][d]
    __shared__ uint16_t KlS[64][72];   // K chunk lo
    __shared__ uint16_t Vs[64][72];    // V chunk [d][key]
    __shared__ __bf16   Ps[QTILE][72]; // P [qrow][key], wave-private rows
    __shared__ int modk_s[64];

    const int bid = blockIdx.x;
    const int wg  = (bid & 7) * 384 + (bid >> 3);   // XCD-contiguous (bt,h)
    const int bh  = wg >> 3;
    const int bt = bh / NHEAD, h = bh % NHEAD;
    const int q0 = (wg & 7) * QTILE;
    const int tid = threadIdx.x, lane = tid & 63, wave = tid >> 6;
    const int quad = lane >> 4, l16 = lane & 15;
    const int wq = wave * 16;

    const size_t hb = (size_t)bh * SEQL * HDIM;
    const int nlat = nlat_p[0];

    // block-uniform needed-tile mask (identical in every wave)
    unsigned needmask;
    {
        int rm = modality[q0 + lane];
        bool hasLat = __any((q0 + lane) < nlat);
        bool has0   = __any(rm == 0);
        bool has1   = __any(rm == 1);
        needmask = 0;
        #pragma unroll
        for (int t8 = 0; t8 < 8; t8++) {
            int km = modality[t8 * 64 + lane];
            bool kb0 = __any(km == 0);
            bool kb1 = __any(km == 1);
            bool need = hasLat || (has0 && kb0) || (has1 && kb1);
            needmask |= (need ? 1u : 0u) << t8;
        }
    }

    bf16x8 qh[2], ql[2];
    #pragma unroll
    for (int ks = 0; ks < 2; ks++) {
        size_t o = hb + (size_t)(q0 + wq + l16) * HDIM + ks*32 + quad*8;
        qh[ks] = *(const bf16x8*)(Qhg + o);
        ql[ks] = *(const bf16x8*)(Qlg + o);
    }

    int  mq[4]; bool lat_[4];
    #pragma unroll
    for (int r = 0; r < 4; r++) {
        int row = q0 + wq + quad*4 + r;
        mq[r]   = modality[row];
        lat_[r] = row < nlat;
    }

    float mrow[4], lrow[4];
    #pragma unroll
    for (int r = 0; r < 4; r++) { mrow[r] = -3e38f; lrow[r] = 0.f; }
    f32x4 O[4];
    #pragma unroll
    for (int dt = 0; dt < 4; dt++) O[dt] = (f32x4){0.f,0.f,0.f,0.f};

    // per-thread staging geometry: 32 B of K-hi, K-lo, V each
    const int rr = tid >> 2, c0 = (tid & 3) * 16;

    uint4 rk0, rk1, rl0, rl1, rv0, rv1;   // in-flight tile registers
    int   rmod = 0;
    auto loadRegs = [&](int t) {
        const int s0 = t * 64;
        const uint16_t* kp = Khg + hb + (size_t)(s0 + rr) * HDIM + c0;
        const uint16_t* lp = Klg + hb + (size_t)(s0 + rr) * HDIM + c0;
        const uint16_t* vp = Vtg + hb + (size_t)rr * SEQL + s0 + c0;  // rr = d
        rk0 = *(const uint4*)kp;       rk1 = *((const uint4*)kp + 1);
        rl0 = *(const uint4*)lp;       rl1 = *((const uint4*)lp + 1);
        rv0 = *(const uint4*)vp;       rv1 = *((const uint4*)vp + 1);
        if (tid < 64) rmod = modality[s0 + tid];
    };

    int t8 = __ffs(needmask) - 1;          // needmask always nonzero
    loadRegs(t8);

    while (t8 >= 0) {
        __syncthreads();                   // WAR: all waves done with K/V LDS
        *(uint4*)&KhS[rr][c0]     = rk0;
        *(uint4*)&KhS[rr][c0 + 8] = rk1;
        *(uint4*)&KlS[rr][c0]     = rl0;
        *(uint4*)&KlS[rr][c0 + 8] = rl1;
        *(uint4*)&Vs[rr][c0]      = rv0;
        *(uint4*)&Vs[rr][c0 + 8]  = rv1;
        if (tid < 64) modk_s[tid] = rmod;
        __syncthreads();                   // RAW: tile visible to all waves

        // issue NEXT needed tile's loads now; latency hides under compute
        int nt8;
        { unsigned rem = needmask >> (t8 + 1);
          nt8 = rem ? (t8 + 1 + __ffs(rem) - 1) : -1; }
        if (nt8 >= 0) loadRegs(nt8);

        // ---- compute on current tile ----
        f32x4 S[4];
        #pragma unroll
        for (int n = 0; n < 4; n++) S[n] = (f32x4){0.f,0.f,0.f,0.f};
        __builtin_amdgcn_s_setprio(1);
        #pragma unroll
        for (int n = 0; n < 4; n++) {
            #pragma unroll
            for (int ks = 0; ks < 2; ks++) {
                bf16x8 kh = *(const bf16x8*)&KhS[n*16 + l16][ks*32 + quad*8];
                bf16x8 kl = *(const bf16x8*)&KlS[n*16 + l16][ks*32 + quad*8];
                S[n] = __builtin_amdgcn_mfma_f32_16x16x32_bf16(ql[ks], kh, S[n], 0, 0, 0);
                S[n] = __builtin_amdgcn_mfma_f32_16x16x32_bf16(qh[ks], kl, S[n], 0, 0, 0);
                S[n] = __builtin_amdgcn_mfma_f32_16x16x32_bf16(qh[ks], kh, S[n], 0, 0, 0);
            }
        }
        __builtin_amdgcn_s_setprio(0);

        int mk[4];
        #pragma unroll
        for (int n = 0; n < 4; n++) mk[n] = modk_s[n*16 + l16];
        #pragma unroll
        for (int n = 0; n < 4; n++)
            #pragma unroll
            for (int r = 0; r < 4; r++)
                if (!(lat_[r] || (mq[r] == mk[n]))) S[n][r] = -3e38f;

        // row max + defer-max gate
        float mc4[4], need = 0.f;
        #pragma unroll
        for (int r = 0; r < 4; r++) {
            float mc = fmaxf(fmaxf(S[0][r], S[1][r]), fmaxf(S[2][r], S[3][r]));
            #pragma unroll
            for (int off = 1; off <= 8; off <<= 1)
                mc = fmaxf(mc, __shfl_xor(mc, off, 64));
            mc4[r] = mc;
            need = fmaxf(need, mc - mrow[r]);
        }
        if (__any(need > 8.0f)) {          // wave-uniform rescale
            #pragma unroll
            for (int r = 0; r < 4; r++) {
                float mn = fmaxf(mrow[r], mc4[r]);
                float al = __expf(mrow[r] - mn);
                mrow[r] = mn;
                lrow[r] *= al;
                #pragma unroll
                for (int dt = 0; dt < 4; dt++) O[dt][r] *= al;
            }
        }
        #pragma unroll
        for (int r = 0; r < 4; r++) {
            float mn = mrow[r];
            float g  = (mn <= -1e37f) ? 0.f : 1.f;
            float sum = 0.f;
            #pragma unroll
            for (int n = 0; n < 4; n++) {
                float p = __expf(S[n][r] - mn) * g;
                Ps[wq + quad*4 + r][n*16 + l16] = (__bf16)p;
                sum += p;
            }
            #pragma unroll
            for (int off = 1; off <= 8; off <<= 1)
                sum += __shfl_xor(sum, off, 64);
            lrow[r] += sum;
        }

        __builtin_amdgcn_s_setprio(1);
        #pragma unroll
        for (int ks = 0; ks < 2; ks++) {
            bf16x8 pa = *(const bf16x8*)&Ps[wq + l16][ks*32 + quad*8];
            #pragma unroll
            for (int dt = 0; dt < 4; dt++) {
                bf16x8 vb = *(const bf16x8*)&Vs[dt*16 + l16][ks*32 + quad*8];
                O[dt] = __builtin_amdgcn_mfma_f32_16x16x32_bf16(pa, vb, O[dt], 0, 0, 0);
            }
        }
        __builtin_amdgcn_s_setprio(0);

        t8 = nt8;
    }

    {
        float inv[4];
        #pragma unroll
        for (int r = 0; r < 4; r++) inv[r] = 1.0f / fmaxf(lrow[r], 1e-30f);
        __bf16* ctxb = (__bf16*)ctx;
        #pragma unroll
        for (int dt = 0; dt < 4; dt++) {
            #pragma unroll
            for (int r = 0; r < 4; r++) {
                int row = q0 + wq + quad*4 + r;
                ctxb[(size_t)(bt * SEQL + row) * DM + h*HDIM + dt*16 + l16] =
                    (__bf16)(O[dt][r] * inv[r]);
            }
        }
    }
}

// ---------------------------------------------------------------------------
extern "C" void kernel_launch(void* const* d_in, const int* in_sizes, int n_in,
                              void* d_out, int out_size, void* d_ws, size_t ws_size,
                              hipStream_t stream) {
    const float* X  = (const float*)d_in[0];
    const float* Wq = (const float*)d_in[1];
    const float* bq = (const float*)d_in[2];
    const float* Wk = (const float*)d_in[3];
    const float* bk = (const float*)d_in[4];
    const float* Wv = (const float*)d_in[5];
    const float* bv = (const float*)d_in[6];
    const float* Wo = (const float*)d_in[7];
    const float* bo = (const float*)d_in[8];
    const int* modality = (const int*)d_in[9];
    const int* nlat     = (const int*)d_in[10];

    const size_t per = (size_t)MTOT * DM;
    const size_t wsz = (size_t)DM * DM;
    uint16_t* p = (uint16_t*)d_ws;
    uint16_t* Xh   = p; p += per;
    uint16_t* Xl   = p; p += per;
    uint16_t* WqTh = p; p += wsz;
    uint16_t* WqTl = p; p += wsz;
    uint16_t* WkTh = p; p += wsz;
    uint16_t* WkTl = p; p += wsz;
    uint16_t* WvT  = p; p += wsz;
    uint16_t* WoT  = p; p += wsz;
    uint16_t* Qh   = p; p += per;
    uint16_t* Ql   = p; p += per;
    uint16_t* Kh   = p; p += per;
    uint16_t* Kl   = p; p += per;
    uint16_t* Vt   = p; p += per;
    uint16_t* c_ws = Xh;   // alias: Xh dead after qkv_gemm_v8

    prep_kernel<<<dim3(12288 + 2304), 256, 0, stream>>>(
        X, Xh, Xl, Wq, Wk, Wv, Wo, WqTh, WqTl, WkTh, WkTl, WvT, WoT);
    qkv_gemm_v8<<<dim3(2304), 256, 0, stream>>>(
        Xh, Xl, WqTh, WqTl, WkTh, WkTl, WvT, bq, bk, bv,
        Qh, Ql, Kh, Kl, Vt);
    attn_mfma_v4<<<dim3(3072), 256, 0, stream>>>(
        Qh, Ql, Kh, Kl, Vt, modality, nlat, c_ws);
    out_proj_v4<<<dim3(768), 256, 0, stream>>>(
        c_ws, WoT, bo, (float*)d_out);
}

// Round 12
// 381.947 us; speedup vs baseline: 1.0319x; 1.0319x over previous
//
#include <hip/hip_runtime.h>
#include <stdint.h>

// Problem constants
#define BT_N  32      // B*T
#define SEQL  512     // S
#define DM    768     // D_MODEL
#define NHEAD 12
#define HDIM  64
#define MTOT  (BT_N * SEQL)   // 16384 rows

typedef __bf16 bf16x8 __attribute__((ext_vector_type(8)));
typedef float  f32x4  __attribute__((ext_vector_type(4)));

__device__ __forceinline__ float b2f(uint16_t u)  { return __uint_as_float(((uint32_t)u) << 16); }
__device__ __forceinline__ uint16_t f2b(float f) {
    uint32_t u = __float_as_uint(f);
    return (uint16_t)((u + 0x7fffu + ((u >> 16) & 1u)) >> 16);  // RNE
}
__device__ __forceinline__ void split_bf16(float x, uint16_t& hi, uint16_t& lo) {
    hi = f2b(x);
    lo = f2b(x - b2f(hi));
}

// global -> LDS DMA, 16 B per lane. LDS dest must be wave-uniform base (+lane*16 implicit).
__device__ __forceinline__ void gload16(const void* g, void* l) {
    __builtin_amdgcn_global_load_lds(
        (const __attribute__((address_space(1))) void*)g,
        (__attribute__((address_space(3))) void*)l,
        16, 0, 0);
}

// ---------------------------------------------------------------------------
// Fused prepass: blocks [0,12288) = X fp32 -> Xh/Xl split;
// [12288,14592) = weight transpose (+split for Wq,Wk).
// ---------------------------------------------------------------------------
__global__ __launch_bounds__(256) void prep_kernel(
    const float* __restrict__ X, uint16_t* __restrict__ Xh, uint16_t* __restrict__ Xl,
    const float* __restrict__ Wq, const float* __restrict__ Wk,
    const float* __restrict__ Wv, const float* __restrict__ Wo,
    uint16_t* __restrict__ WqTh, uint16_t* __restrict__ WqTl,
    uint16_t* __restrict__ WkTh, uint16_t* __restrict__ WkTl,
    uint16_t* __restrict__ WvT,  uint16_t* __restrict__ WoT)
{
    __shared__ float tile[32][33];
    const int bid = blockIdx.x;
    const int tid = threadIdx.x;

    if (bid < 12288) {                       // ---- split_x ----
        size_t i = ((size_t)bid * 256 + tid) * 4;
        float4 v = *(const float4*)(X + i);
        float xx[4] = {v.x, v.y, v.z, v.w};
        ushort4 h, l;
        uint16_t hh, ll;
        split_bf16(xx[0], hh, ll); h.x = hh; l.x = ll;
        split_bf16(xx[1], hh, ll); h.y = hh; l.y = ll;
        split_bf16(xx[2], hh, ll); h.z = hh; l.z = ll;
        split_bf16(xx[3], hh, ll); h.w = hh; l.w = ll;
        *(ushort4*)(Xh + i) = h;
        *(ushort4*)(Xl + i) = l;
        return;
    }

    // ---- wprep ----
    const int wid = bid - 12288;             // 0..2303
    const int z   = wid / 576;
    const int rem = wid % 576;
    const int k0 = (rem % 24) * 32, n0 = (rem / 24) * 32;

    const float* W; uint16_t* Th; uint16_t* Tl;
    if (z == 0)      { W = Wq; Th = WqTh; Tl = WqTl; }
    else if (z == 1) { W = Wk; Th = WkTh; Tl = WkTl; }
    else if (z == 2) { W = Wv; Th = WvT;  Tl = nullptr; }
    else             { W = Wo; Th = WoT;  Tl = nullptr; }

    {
        int r = tid >> 3, c = (tid & 7) * 4;
        *(float4*)&tile[r][c] = *(const float4*)(W + (size_t)(k0 + r) * DM + n0 + c);
    }
    __syncthreads();
    {
        int nl = tid >> 3, kk = (tid & 7) * 4;
        ushort4 h, l;
        uint16_t hh, ll;
        float v0 = tile[kk + 0][nl], v1 = tile[kk + 1][nl];
        float v2 = tile[kk + 2][nl], v3 = tile[kk + 3][nl];
        split_bf16(v0, hh, ll); h.x = hh; l.x = ll;
        split_bf16(v1, hh, ll); h.y = hh; l.y = ll;
        split_bf16(v2, hh, ll); h.z = hh; l.z = ll;
        split_bf16(v3, hh, ll); h.w = hh; l.w = ll;
        size_t o = (size_t)(n0 + nl) * DM + k0 + kk;
        *(ushort4*)(Th + o) = h;
        if (Tl) *(ushort4*)(Tl + o) = l;
    }
}

// ---------------------------------------------------------------------------
// Fused QKV GEMM v7 — CONCATENATED, not interleaved:
//   bid in [0,1536):    qk path, proven 3D x-fastest order
//   bid in [1536,2304): V path, proven XCD swizzle
// Bulk phase is pure-qk (identical L2 locality to separate launches); v blocks
// backfill qk's tail drain. Verified best: 148µs, FETCH 110MB, wall 383.6µs.
// ---------------------------------------------------------------------------
__global__ __launch_bounds__(256, 2) void qkv_gemm_v7(
    const uint16_t* __restrict__ Xh, const uint16_t* __restrict__ Xl,
    const uint16_t* __restrict__ WqTh, const uint16_t* __restrict__ WqTl,
    const uint16_t* __restrict__ WkTh, const uint16_t* __restrict__ WkTl,
    const uint16_t* __restrict__ WvT,
    const float* __restrict__ bq, const float* __restrict__ bk,
    const float* __restrict__ bv,
    uint16_t* __restrict__ Qh, uint16_t* __restrict__ Ql,
    uint16_t* __restrict__ Kh, uint16_t* __restrict__ Kl,
    uint16_t* __restrict__ Vt)
{
    __shared__ uint16_t lds[2][16384];   // 2 x 32 KB

    const int bid  = blockIdx.x;
    const int tid  = threadIdx.x;
    const int lane = tid & 63, wave = tid >> 6;
    const int quad = lane >> 4, l16 = lane & 15;
    const int wm = (wave >> 1) * 64, wn = (wave & 1) * 64;

    if (bid < 1536) {
        // ================= QK path (split-bf16), x-fastest order =================
        const int m0 = (bid & 127) * 128;
        const int n0 = ((bid >> 7) % 6) * 128;
        const int z  = bid / 768;

        const uint16_t* Bh_g = z ? WkTh : WqTh;
        const uint16_t* Bl_g = z ? WkTl : WqTl;
        const float* bias    = z ? bk : bq;
        uint16_t* OutH       = z ? Kh : Qh;
        uint16_t* OutL       = z ? Kl : Ql;
        const float scale    = z ? 1.0f : 0.125f;

        const uint16_t* src[8];
        #pragma unroll
        for (int i = 0; i < 8; i++) {
            int d    = (i * 256 + tid) * 16;
            int row  = (d >> 7) & 127;
            int colb = d & 127;
            int scol = colb ^ ((row & 7) << 4);      // involution
            int kofs = (scol & 63) >> 1;             // 0..31 elems within k-window
            const uint16_t* g;
            if (d < 16384) g = (scol < 64 ? Xh : Xl)     + (size_t)(m0 + row) * DM + kofs;
            else           g = (scol < 64 ? Bh_g : Bl_g) + (size_t)(n0 + row) * DM + kofs;
            src[i] = g;
        }

        int offA[4], offB[4];
        #pragma unroll
        for (int i = 0; i < 4; i++) {
            int r  = wm + i * 16 + l16;
            offA[i] = r * 64 + (((quad * 16) ^ ((r & 7) << 4)) >> 1);
            int rb = wn + i * 16 + l16;
            offB[i] = 8192 + rb * 64 + (((quad * 16) ^ ((rb & 7) << 4)) >> 1);
        }

        f32x4 acc[4][4];
        #pragma unroll
        for (int i = 0; i < 4; i++)
            #pragma unroll
            for (int j = 0; j < 4; j++) acc[i][j] = (f32x4){0.f,0.f,0.f,0.f};

        auto stage = [&](int buf) {
            #pragma unroll
            for (int i = 0; i < 8; i++) {
                gload16(src[i], &lds[buf][(i * 256 + wave * 64) * 8]);
                src[i] += 32;                        // advance one BK=32 window
            }
        };
        auto computeTile = [&](int buf) {
            const uint16_t* base = &lds[buf][0];
            bf16x8 ah[4], al[4], bh[4], bl[4];
            #pragma unroll
            for (int i = 0; i < 4; i++) {
                ah[i] = *(const bf16x8*)(base + offA[i]);
                al[i] = *(const bf16x8*)(base + (offA[i] ^ 32));
                bh[i] = *(const bf16x8*)(base + offB[i]);
                bl[i] = *(const bf16x8*)(base + (offB[i] ^ 32));
            }
            #pragma unroll
            for (int mi = 0; mi < 4; mi++)
                #pragma unroll
                for (int ni = 0; ni < 4; ni++) {
                    acc[mi][ni] = __builtin_amdgcn_mfma_f32_16x16x32_bf16(al[mi], bh[ni], acc[mi][ni], 0, 0, 0);
                    acc[mi][ni] = __builtin_amdgcn_mfma_f32_16x16x32_bf16(ah[mi], bl[ni], acc[mi][ni], 0, 0, 0);
                    acc[mi][ni] = __builtin_amdgcn_mfma_f32_16x16x32_bf16(ah[mi], bh[ni], acc[mi][ni], 0, 0, 0);
                }
        };

        stage(0);
        asm volatile("s_waitcnt vmcnt(0)" ::: "memory");
        __syncthreads();

        int cur = 0;
        for (int t = 0; t < 23; t++) {               // 24 k-steps total (768/32)
            stage(cur ^ 1);
            computeTile(cur);
            asm volatile("s_waitcnt vmcnt(0)" ::: "memory");
            __syncthreads();
            cur ^= 1;
        }
        computeTile(cur);

        // epilogue: split-bf16 store to (bt,h,s,d)
        #pragma unroll
        for (int i = 0; i < 4; i++) {
            #pragma unroll
            for (int j = 0; j < 4; j++) {
                int n = n0 + wn + j * 16 + l16;
                float bsv = bias[n];
                int hh = n >> 6, dd = n & 63;
                int mb = m0 + wm + i * 16 + quad * 4;
                #pragma unroll
                for (int r = 0; r < 4; r++) {
                    int m = mb + r;
                    float val = (acc[i][j][r] + bsv) * scale;
                    uint16_t vh, vl; split_bf16(val, vh, vl);
                    int bt = m >> 9, s = m & 511;
                    size_t idx = (((size_t)bt * NHEAD + hh) * SEQL + s) * HDIM + dd;
                    OutH[idx] = vh; OutL[idx] = vl;
                }
            }
        }
    } else {
        // ================= V path (plain bf16), XCD swizzle =================
        const int v_id = bid - 1536;                 // 0..767
        const int wg  = (v_id & 7) * 96 + (v_id >> 3);
        const int m0  = (wg / 6) * 128;
        const int n0  = (wg % 6) * 128;

        const uint16_t* src[8];
        #pragma unroll
        for (int i = 0; i < 8; i++) {
            int d    = (i * 256 + tid) * 16;
            int row  = (d >> 7) & 127;
            int colb = d & 127;
            int scol = colb ^ ((row & 7) << 4);
            int kofs = scol >> 1;                    // 0..63
            src[i] = (d < 16384 ? Xh + (size_t)(m0 + row) * DM
                                : WvT + (size_t)(n0 + row) * DM) + kofs;
        }

        int offA[4], offB[4];
        #pragma unroll
        for (int i = 0; i < 4; i++) {
            int r  = wm + i * 16 + l16;
            offA[i] = r * 64 + (((quad * 16) ^ ((r & 7) << 4)) >> 1);
            int rb = wn + i * 16 + l16;
            offB[i] = 8192 + rb * 64 + (((quad * 16) ^ ((rb & 7) << 4)) >> 1);
        }

        f32x4 acc[4][4];
        #pragma unroll
        for (int i = 0; i < 4; i++)
            #pragma unroll
            for (int j = 0; j < 4; j++) acc[i][j] = (f32x4){0.f,0.f,0.f,0.f};

        auto stage = [&](int buf) {
            #pragma unroll
            for (int i = 0; i < 8; i++) {
                gload16(src[i], &lds[buf][(i * 256 + wave * 64) * 8]);
                src[i] += 64;
            }
        };
        auto computeTile = [&](int buf) {
            const uint16_t* base = &lds[buf][0];
            bf16x8 a0[4], a1[4], b0[4], b1[4];
            #pragma unroll
            for (int i = 0; i < 4; i++) {
                a0[i] = *(const bf16x8*)(base + offA[i]);
                a1[i] = *(const bf16x8*)(base + (offA[i] ^ 32));
                b0[i] = *(const bf16x8*)(base + offB[i]);
                b1[i] = *(const bf16x8*)(base + (offB[i] ^ 32));
            }
            #pragma unroll
            for (int mi = 0; mi < 4; mi++)
                #pragma unroll
                for (int ni = 0; ni < 4; ni++)
                    acc[mi][ni] = __builtin_amdgcn_mfma_f32_16x16x32_bf16(a0[mi], b0[ni], acc[mi][ni], 0, 0, 0);
            #pragma unroll
            for (int mi = 0; mi < 4; mi++)
                #pragma unroll
                for (int ni = 0; ni < 4; ni++)
                    acc[mi][ni] = __builtin_amdgcn_mfma_f32_16x16x32_bf16(a1[mi], b1[ni], acc[mi][ni], 0, 0, 0);
        };

        stage(0);
        asm volatile("s_waitcnt vmcnt(0)" ::: "memory");
        __syncthreads();

        int cur = 0;
        for (int t = 0; t < 11; t++) {               // 12 k-steps (768/64)
            stage(cur ^ 1);
            computeTile(cur);
            asm volatile("s_waitcnt vmcnt(0)" ::: "memory");
            __syncthreads();
            cur ^= 1;
        }
        computeTile(cur);

        #pragma unroll
        for (int i = 0; i < 4; i++) {
            #pragma unroll
            for (int j = 0; j < 4; j++) {
                int n = n0 + wn + j * 16 + l16;
                float bsv = bv[n];
                int hh = n >> 6, dd = n & 63;
                int mb = m0 + wm + i * 16 + quad * 4;
                int bt = mb >> 9, sb = mb & 511;
                ushort4 pk;
                pk.x = f2b(acc[i][j][0] + bsv);
                pk.y = f2b(acc[i][j][1] + bsv);
                pk.z = f2b(acc[i][j][2] + bsv);
                pk.w = f2b(acc[i][j][3] + bsv);
                *(ushort4*)&Vt[(((size_t)bt * NHEAD + hh) * HDIM + dd) * SEQL + sb] = pk;
            }
        }
    }
}

// ---------------------------------------------------------------------------
// Output projection v3: 2-phase structure + XCD swizzle (grid 768 1D).
// ---------------------------------------------------------------------------
__global__ __launch_bounds__(256, 2) void out_proj_v3(
    const uint16_t* __restrict__ A, const uint16_t* __restrict__ WoT,
    const float* __restrict__ bias, float* __restrict__ Y)
{
    __shared__ uint16_t lds[2][16384];

    const int bid = blockIdx.x;
    const int wg  = (bid & 7) * 96 + (bid >> 3);
    const int m0  = (wg / 6) * 128;
    const int n0  = (wg % 6) * 128;

    const int tid  = threadIdx.x;
    const int lane = tid & 63, wave = tid >> 6;
    const int quad = lane >> 4, l16 = lane & 15;
    const int wm = (wave >> 1) * 64, wn = (wave & 1) * 64;

    const uint16_t* src[8];
    #pragma unroll
    for (int i = 0; i < 8; i++) {
        int d    = (i * 256 + tid) * 16;
        int row  = (d >> 7) & 127;
        int colb = d & 127;
        int scol = colb ^ ((row & 7) << 4);
        int kofs = scol >> 1;
        src[i] = (d < 16384 ? A + (size_t)(m0 + row) * DM
                            : WoT + (size_t)(n0 + row) * DM) + kofs;
    }

    int offA[4], offB[4];
    #pragma unroll
    for (int i = 0; i < 4; i++) {
        int r  = wm + i * 16 + l16;
        offA[i] = r * 64 + (((quad * 16) ^ ((r & 7) << 4)) >> 1);
        int rb = wn + i * 16 + l16;
        offB[i] = 8192 + rb * 64 + (((quad * 16) ^ ((rb & 7) << 4)) >> 1);
    }

    f32x4 acc[4][4];
    #pragma unroll
    for (int i = 0; i < 4; i++)
        #pragma unroll
        for (int j = 0; j < 4; j++) acc[i][j] = (f32x4){0.f,0.f,0.f,0.f};

    auto stage = [&](int buf) {
        #pragma unroll
        for (int i = 0; i < 8; i++) {
            gload16(src[i], &lds[buf][(i * 256 + wave * 64) * 8]);
            src[i] += 64;
        }
    };
    auto computeTile = [&](int buf) {
        const uint16_t* base = &lds[buf][0];
        bf16x8 a0[4], a1[4], b0[4], b1[4];
        #pragma unroll
        for (int i = 0; i < 4; i++) {
            a0[i] = *(const bf16x8*)(base + offA[i]);
            a1[i] = *(const bf16x8*)(base + (offA[i] ^ 32));
            b0[i] = *(const bf16x8*)(base + offB[i]);
            b1[i] = *(const bf16x8*)(base + (offB[i] ^ 32));
        }
        #pragma unroll
        for (int mi = 0; mi < 4; mi++)
            #pragma unroll
            for (int ni = 0; ni < 4; ni++)
                acc[mi][ni] = __builtin_amdgcn_mfma_f32_16x16x32_bf16(a0[mi], b0[ni], acc[mi][ni], 0, 0, 0);
        #pragma unroll
        for (int mi = 0; mi < 4; mi++)
            #pragma unroll
            for (int ni = 0; ni < 4; ni++)
                acc[mi][ni] = __builtin_amdgcn_mfma_f32_16x16x32_bf16(a1[mi], b1[ni], acc[mi][ni], 0, 0, 0);
    };

    stage(0);
    asm volatile("s_waitcnt vmcnt(0)" ::: "memory");
    __syncthreads();

    int cur = 0;
    for (int t = 0; t < 11; t++) {
        stage(cur ^ 1);
        computeTile(cur);
        asm volatile("s_waitcnt vmcnt(0)" ::: "memory");
        __syncthreads();
        cur ^= 1;
    }
    computeTile(cur);

    #pragma unroll
    for (int i = 0; i < 4; i++) {
        #pragma unroll
        for (int j = 0; j < 4; j++) {
            int n = n0 + wn + j * 16 + l16;
            float bsv = bias[n];
            int mb = m0 + wm + i * 16 + quad * 4;
            #pragma unroll
            for (int r = 0; r < 4; r++)
                Y[(size_t)(mb + r) * DM + n] = acc[i][j][r] + bsv;
        }
    }
}

// ---------------------------------------------------------------------------
// MFMA flash attention v4: LDS staging + T14 async-STAGE split, tile skip,
// defer-max, XCD swizzle.
// ---------------------------------------------------------------------------
#define QTILE 64

__global__ __launch_bounds__(256) void attn_mfma_v4(
    const uint16_t* __restrict__ Qhg, const uint16_t* __restrict__ Qlg,
    const uint16_t* __restrict__ Khg, const uint16_t* __restrict__ Klg,
    const uint16_t* __restrict__ Vtg, const int* __restrict__ modality,
    const int* __restrict__ nlat_p, uint16_t* __restrict__ ctx)
{
    __shared__ uint16_t KhS[64][72];   // K chunk hi [key][d]
    __shared__ uint16_t KlS[64][72];   // K chunk lo
    __shared__ uint16_t Vs[64][72];    // V chunk [d][key]
    __shared__ __bf16   Ps[QTILE][72]; // P [qrow][key], wave-private rows
    __shared__ int modk_s[64];

    const int bid = blockIdx.x;
    const int wg  = (bid & 7) * 384 + (bid >> 3);   // XCD-contiguous (bt,h)
    const int bh  = wg >> 3;
    const int bt = bh / NHEAD, h = bh % NHEAD;
    const int q0 = (wg & 7) * QTILE;
    const int tid = threadIdx.x, lane = tid & 63, wave = tid >> 6;
    const int quad = lane >> 4, l16 = lane & 15;
    const int wq = wave * 16;

    const size_t hb = (size_t)bh * SEQL * HDIM;
    const int nlat = nlat_p[0];

    // block-uniform needed-tile mask (identical in every wave)
    unsigned needmask;
    {
        int rm = modality[q0 + lane];
        bool hasLat = __any((q0 + lane) < nlat);
        bool has0   = __any(rm == 0);
        bool has1   = __any(rm == 1);
        needmask = 0;
        #pragma unroll
        for (int t8 = 0; t8 < 8; t8++) {
            int km = modality[t8 * 64 + lane];
            bool kb0 = __any(km == 0);
            bool kb1 = __any(km == 1);
            bool need = hasLat || (has0 && kb0) || (has1 && kb1);
            needmask |= (need ? 1u : 0u) << t8;
        }
    }

    bf16x8 qh[2], ql[2];
    #pragma unroll
    for (int ks = 0; ks < 2; ks++) {
        size_t o = hb + (size_t)(q0 + wq + l16) * HDIM + ks*32 + quad*8;
        qh[ks] = *(const bf16x8*)(Qhg + o);
        ql[ks] = *(const bf16x8*)(Qlg + o);
    }

    int  mq[4]; bool lat_[4];
    #pragma unroll
    for (int r = 0; r < 4; r++) {
        int row = q0 + wq + quad*4 + r;
        mq[r]   = modality[row];
        lat_[r] = row < nlat;
    }

    float mrow[4], lrow[4];
    #pragma unroll
    for (int r = 0; r < 4; r++) { mrow[r] = -3e38f; lrow[r] = 0.f; }
    f32x4 O[4];
    #pragma unroll
    for (int dt = 0; dt < 4; dt++) O[dt] = (f32x4){0.f,0.f,0.f,0.f};

    // per-thread staging geometry: 32 B of K-hi, K-lo, V each
    const int rr = tid >> 2, c0 = (tid & 3) * 16;

    uint4 rk0, rk1, rl0, rl1, rv0, rv1;   // in-flight tile registers
    int   rmod = 0;
    auto loadRegs = [&](int t) {
        const int s0 = t * 64;
        const uint16_t* kp = Khg + hb + (size_t)(s0 + rr) * HDIM + c0;
        const uint16_t* lp = Klg + hb + (size_t)(s0 + rr) * HDIM + c0;
        const uint16_t* vp = Vtg + hb + (size_t)rr * SEQL + s0 + c0;  // rr = d
        rk0 = *(const uint4*)kp;       rk1 = *((const uint4*)kp + 1);
        rl0 = *(const uint4*)lp;       rl1 = *((const uint4*)lp + 1);
        rv0 = *(const uint4*)vp;       rv1 = *((const uint4*)vp + 1);
        if (tid < 64) rmod = modality[s0 + tid];
    };

    int t8 = __ffs(needmask) - 1;          // needmask always nonzero
    loadRegs(t8);

    while (t8 >= 0) {
        __syncthreads();                   // WAR: all waves done with K/V LDS
        *(uint4*)&KhS[rr][c0]     = rk0;
        *(uint4*)&KhS[rr][c0 + 8] = rk1;
        *(uint4*)&KlS[rr][c0]     = rl0;
        *(uint4*)&KlS[rr][c0 + 8] = rl1;
        *(uint4*)&Vs[rr][c0]      = rv0;
        *(uint4*)&Vs[rr][c0 + 8]  = rv1;
        if (tid < 64) modk_s[tid] = rmod;
        __syncthreads();                   // RAW: tile visible to all waves

        // issue NEXT needed tile's loads now; latency hides under compute
        int nt8;
        { unsigned rem = needmask >> (t8 + 1);
          nt8 = rem ? (t8 + 1 + __ffs(rem) - 1) : -1; }
        if (nt8 >= 0) loadRegs(nt8);

        // ---- compute on current tile ----
        f32x4 S[4];
        #pragma unroll
        for (int n = 0; n < 4; n++) S[n] = (f32x4){0.f,0.f,0.f,0.f};
        __builtin_amdgcn_s_setprio(1);
        #pragma unroll
        for (int n = 0; n < 4; n++) {
            #pragma unroll
            for (int ks = 0; ks < 2; ks++) {
                bf16x8 kh = *(const bf16x8*)&KhS[n*16 + l16][ks*32 + quad*8];
                bf16x8 kl = *(const bf16x8*)&KlS[n*16 + l16][ks*32 + quad*8];
                S[n] = __builtin_amdgcn_mfma_f32_16x16x32_bf16(ql[ks], kh, S[n], 0, 0, 0);
                S[n] = __builtin_amdgcn_mfma_f32_16x16x32_bf16(qh[ks], kl, S[n], 0, 0, 0);
                S[n] = __builtin_amdgcn_mfma_f32_16x16x32_bf16(qh[ks], kh, S[n], 0, 0, 0);
            }
        }
        __builtin_amdgcn_s_setprio(0);

        int mk[4];
        #pragma unroll
        for (int n = 0; n < 4; n++) mk[n] = modk_s[n*16 + l16];
        #pragma unroll
        for (int n = 0; n < 4; n++)
            #pragma unroll
            for (int r = 0; r < 4; r++)
                if (!(lat_[r] || (mq[r] == mk[n]))) S[n][r] = -3e38f;

        // row max + defer-max gate
        float mc4[4], need = 0.f;
        #pragma unroll
        for (int r = 0; r < 4; r++) {
            float mc = fmaxf(fmaxf(S[0][r], S[1][r]), fmaxf(S[2][r], S[3][r]));
            #pragma unroll
            for (int off = 1; off <= 8; off <<= 1)
                mc = fmaxf(mc, __shfl_xor(mc, off, 64));
            mc4[r] = mc;
            need = fmaxf(need, mc - mrow[r]);
        }
        if (__any(need > 8.0f)) {          // wave-uniform rescale
            #pragma unroll
            for (int r = 0; r < 4; r++) {
                float mn = fmaxf(mrow[r], mc4[r]);
                float al = __expf(mrow[r] - mn);
                mrow[r] = mn;
                lrow[r] *= al;
                #pragma unroll
                for (int dt = 0; dt < 4; dt++) O[dt][r] *= al;
            }
        }
        #pragma unroll
        for (int r = 0; r < 4; r++) {
            float mn = mrow[r];
            float g  = (mn <= -1e37f) ? 0.f : 1.f;
            float sum = 0.f;
            #pragma unroll
            for (int n = 0; n < 4; n++) {
                float p = __expf(S[n][r] - mn) * g;
                Ps[wq + quad*4 + r][n*16 + l16] = (__bf16)p;
                sum += p;
            }
            #pragma unroll
            for (int off = 1; off <= 8; off <<= 1)
                sum += __shfl_xor(sum, off, 64);
            lrow[r] += sum;
        }

        __builtin_amdgcn_s_setprio(1);
        #pragma unroll
        for (int ks = 0; ks < 2; ks++) {
            bf16x8 pa = *(const bf16x8*)&Ps[wq + l16][ks*32 + quad*8];
            #pragma unroll
            for (int dt = 0; dt < 4; dt++) {
                bf16x8 vb = *(const bf16x8*)&Vs[dt*16 + l16][ks*32 + quad*8];
                O[dt] = __builtin_amdgcn_mfma_f32_16x16x32_bf16(pa, vb, O[dt], 0, 0, 0);
            }
        }
        __builtin_amdgcn_s_setprio(0);

        t8 = nt8;
    }

    {
        float inv[4];
        #pragma unroll
        for (int r = 0; r < 4; r++) inv[r] = 1.0f / fmaxf(lrow[r], 1e-30f);
        __bf16* ctxb = (__bf16*)ctx;
        #pragma unroll
        for (int dt = 0; dt < 4; dt++) {
            #pragma unroll
            for (int r = 0; r < 4; r++) {
                int row = q0 + wq + quad*4 + r;
                ctxb[(size_t)(bt * SEQL + row) * DM + h*HDIM + dt*16 + l16] =
                    (__bf16)(O[dt][r] * inv[r]);
            }
        }
    }
}

// ---------------------------------------------------------------------------
extern "C" void kernel_launch(void* const* d_in, const int* in_sizes, int n_in,
                              void* d_out, int out_size, void* d_ws, size_t ws_size,
                              hipStream_t stream) {
    const float* X  = (const float*)d_in[0];
    const float* Wq = (const float*)d_in[1];
    const float* bq = (const float*)d_in[2];
    const float* Wk = (const float*)d_in[3];
    const float* bk = (const float*)d_in[4];
    const float* Wv = (const float*)d_in[5];
    const float* bv = (const float*)d_in[6];
    const float* Wo = (const float*)d_in[7];
    const float* bo = (const float*)d_in[8];
    const int* modality = (const int*)d_in[9];
    const int* nlat     = (const int*)d_in[10];

    const size_t per = (size_t)MTOT * DM;
    const size_t wsz = (size_t)DM * DM;
    uint16_t* p = (uint16_t*)d_ws;
    uint16_t* Xh   = p; p += per;
    uint16_t* Xl   = p; p += per;
    uint16_t* WqTh = p; p += wsz;
    uint16_t* WqTl = p; p += wsz;
    uint16_t* WkTh = p; p += wsz;
    uint16_t* WkTl = p; p += wsz;
    uint16_t* WvT  = p; p += wsz;
    uint16_t* WoT  = p; p += wsz;
    uint16_t* Qh   = p; p += per;
    uint16_t* Ql   = p; p += per;
    uint16_t* Kh   = p; p += per;
    uint16_t* Kl   = p; p += per;
    uint16_t* Vt   = p; p += per;
    uint16_t* c_ws = Xh;   // alias: Xh dead after qkv_gemm_v7

    prep_kernel<<<dim3(12288 + 2304), 256, 0, stream>>>(
        X, Xh, Xl, Wq, Wk, Wv, Wo, WqTh, WqTl, WkTh, WkTl, WvT, WoT);
    qkv_gemm_v7<<<dim3(2304), 256, 0, stream>>>(
        Xh, Xl, WqTh, WqTl, WkTh, WkTl, WvT, bq, bk, bv,
        Qh, Ql, Kh, Kl, Vt);
    attn_mfma_v4<<<dim3(3072), 256, 0, stream>>>(
        Qh, Ql, Kh, Kl, Vt, modality, nlat, c_ws);
    out_proj_v3<<<dim3(768), 256, 0, stream>>>(
        c_ws, WoT, bo, (float*)d_out);
}